// Round 7
// baseline (307.561 us; speedup 1.0000x reference)
//
#include <hip/hip_runtime.h>

typedef __attribute__((ext_vector_type(8))) __bf16 bf16x8;
typedef __attribute__((ext_vector_type(4))) float f32x4;
typedef __attribute__((ext_vector_type(8))) unsigned short ushort8;

#define DSAMP 512
#define DIM   128
#define REG5  16384                // one staged A region: 128 rows * 128 B (bf16, swizzled)
#define NPAIR 18                   // paired tiles per batch (2 tiles per block)

// ---------------------------------------------------------------------------
// Single-pass fused kernel, v5 (resubmit after infra failure in R6; logic
// identical). B never touches LDS: R5 counters showed the v4 structure was
// barrier/latency-bound (MfmaUtil 8.8, VALU 35, HBM 7%, occ 30% — nothing
// saturated, 10 barriers/block). v5 loads B MFMA fragments DIRECTLY from
// global (L3-resident) as 2x float4 + in-register bf16 cvt; B row norms
// fold into the same loads via shfl_xor(16/32) over the kq lanes. LDS holds
// only the A panel (32 KB). Barriers: 2 per block total. After phase S every
// wave runs fully independently -> latency hidden by TLP.
// NOTE: no ^sw on global B cols — the swizzle only matched the LDS write
// pattern; A (still LDS-staged) keeps it.
// ---------------------------------------------------------------------------
__constant__ unsigned char T_Asrc[NPAIR]  = {0,0,0,0,0,0,0,0, 1,1,1,1,1,1,1,1,1,1};
__constant__ unsigned char T_Ai[NPAIR]    = {0,0,1,1,1,2,2,3, 0,0,0,0,1,1,1,2,2,3};
__constant__ unsigned char T_Bsrc0[NPAIR] = {0,0,0,0,1,0,1,0, 1,1,0,0,1,1,0,1,0,1};
__constant__ unsigned char T_Bsrc1[NPAIR] = {0,0,0,1,1,0,1,1, 1,1,0,0,1,0,0,1,0,0};
__constant__ unsigned char T_Bj0[NPAIR]   = {0,2,1,3,2,2,2,3, 0,2,0,2,1,3,2,2,0,3};
__constant__ unsigned char T_Bj1[NPAIR]   = {1,3,2,1,3,3,3,3, 1,3,1,3,2,0,3,3,3,0};
// weight codes: 0 -> +1.0 (xy), 1 -> -1.0 (xx/yy off-diag), 2 -> -0.5 (diag)
__constant__ char          T_wc0[NPAIR]   = {2,1,2,1,0,2,0,2, 2,1,0,0,2,1,0,2,0,2};
__constant__ char          T_wc1[NPAIR]   = {1,1,1,0,0,1,0,0, 1,1,0,0,1,0,0,1,0,0};
__constant__ unsigned char T_d0[NPAIR]    = {1,0,1,0,0,1,0,1, 1,0,0,0,1,0,0,1,0,1};

// arrayless fp32x8 -> bf16x8 RNE convert + sum of squares (all SSA values)
__device__ __forceinline__ ushort8 cvt8(float4 v0, float4 v1, float& ss) {
    ss = v0.x * v0.x + v0.y * v0.y + v0.z * v0.z + v0.w * v0.w
       + v1.x * v1.x + v1.y * v1.y + v1.z * v1.z + v1.w * v1.w;
    ushort8 hv;
    unsigned u;
    u = __float_as_uint(v0.x); hv[0] = (unsigned short)((u + 0x7fffu + ((u >> 16) & 1u)) >> 16);
    u = __float_as_uint(v0.y); hv[1] = (unsigned short)((u + 0x7fffu + ((u >> 16) & 1u)) >> 16);
    u = __float_as_uint(v0.z); hv[2] = (unsigned short)((u + 0x7fffu + ((u >> 16) & 1u)) >> 16);
    u = __float_as_uint(v0.w); hv[3] = (unsigned short)((u + 0x7fffu + ((u >> 16) & 1u)) >> 16);
    u = __float_as_uint(v1.x); hv[4] = (unsigned short)((u + 0x7fffu + ((u >> 16) & 1u)) >> 16);
    u = __float_as_uint(v1.y); hv[5] = (unsigned short)((u + 0x7fffu + ((u >> 16) & 1u)) >> 16);
    u = __float_as_uint(v1.z); hv[6] = (unsigned short)((u + 0x7fffu + ((u >> 16) & 1u)) >> 16);
    u = __float_as_uint(v1.w); hv[7] = (unsigned short)((u + 0x7fffu + ((u >> 16) & 1u)) >> 16);
    return hv;
}

__device__ __forceinline__ bf16x8 cvt8b(float4 v0, float4 v1, float& ss) {
    ushort8 h = cvt8(v0, v1, ss);
    return __builtin_bit_cast(bf16x8, h);
}

#define MFMA16() do {                                                          \
    acc[0][0] = __builtin_amdgcn_mfma_f32_16x16x32_bf16(ah0, bh0, acc[0][0], 0, 0, 0); \
    acc[0][1] = __builtin_amdgcn_mfma_f32_16x16x32_bf16(ah0, bh1, acc[0][1], 0, 0, 0); \
    acc[0][2] = __builtin_amdgcn_mfma_f32_16x16x32_bf16(ah0, bh2, acc[0][2], 0, 0, 0); \
    acc[0][3] = __builtin_amdgcn_mfma_f32_16x16x32_bf16(ah0, bh3, acc[0][3], 0, 0, 0); \
    acc[1][0] = __builtin_amdgcn_mfma_f32_16x16x32_bf16(ah1, bh0, acc[1][0], 0, 0, 0); \
    acc[1][1] = __builtin_amdgcn_mfma_f32_16x16x32_bf16(ah1, bh1, acc[1][1], 0, 0, 0); \
    acc[1][2] = __builtin_amdgcn_mfma_f32_16x16x32_bf16(ah1, bh2, acc[1][2], 0, 0, 0); \
    acc[1][3] = __builtin_amdgcn_mfma_f32_16x16x32_bf16(ah1, bh3, acc[1][3], 0, 0, 0); \
    acc[2][0] = __builtin_amdgcn_mfma_f32_16x16x32_bf16(ah2, bh0, acc[2][0], 0, 0, 0); \
    acc[2][1] = __builtin_amdgcn_mfma_f32_16x16x32_bf16(ah2, bh1, acc[2][1], 0, 0, 0); \
    acc[2][2] = __builtin_amdgcn_mfma_f32_16x16x32_bf16(ah2, bh2, acc[2][2], 0, 0, 0); \
    acc[2][3] = __builtin_amdgcn_mfma_f32_16x16x32_bf16(ah2, bh3, acc[2][3], 0, 0, 0); \
    acc[3][0] = __builtin_amdgcn_mfma_f32_16x16x32_bf16(ah3, bh0, acc[3][0], 0, 0, 0); \
    acc[3][1] = __builtin_amdgcn_mfma_f32_16x16x32_bf16(ah3, bh1, acc[3][1], 0, 0, 0); \
    acc[3][2] = __builtin_amdgcn_mfma_f32_16x16x32_bf16(ah3, bh2, acc[3][2], 0, 0, 0); \
    acc[3][3] = __builtin_amdgcn_mfma_f32_16x16x32_bf16(ah3, bh3, acc[3][3], 0, 0, 0); \
} while (0)

__global__ __launch_bounds__(256, 3)
void mmd_fused(const float* __restrict__ x, const float* __restrict__ y,
               float* __restrict__ partials) {
    __shared__ __align__(16) char smem[2 * REG5];   // A c0 | A c1 (32 KB only)
    __shared__ float Pn[128];
    __shared__ float wred[4];

    const int tid = threadIdx.x;
    const int bid = blockIdx.x;
    const int xcd = bid & 7;
    const int seq = bid >> 3;            // 0..287
    const int s   = seq % NPAIR;
    const int grp = seq / NPAIR;         // 0..15
    const int b   = xcd + 8 * grp;       // batch; all 18 pair-blocks adjacent

    const int Ai  = T_Ai[s];
    const int Bj0 = T_Bj0[s];
    const int Bj1 = T_Bj1[s];
    const float* Asrc  = T_Asrc[s]  ? y : x;
    const float* B0src = T_Bsrc0[s] ? y : x;
    const float* B1src = T_Bsrc1[s] ? y : x;
    const int wc0 = T_wc0[s], wc1 = T_wc1[s];
    const float w0 = (wc0 == 0) ? 1.0f : ((wc0 == 1) ? -1.0f : -0.5f);
    const float w1 = (wc1 == 0) ? 1.0f : ((wc1 == 1) ? -1.0f : -0.5f);
    const bool dg0 = T_d0[s] != 0;

    const size_t rowbase = (size_t)b * 512;
    const float* Ap  = Asrc  + (rowbase + (size_t)Ai  * 128) * 128;
    const float* Bp0 = B0src + (rowbase + (size_t)Bj0 * 128) * 128;
    const float* Bp1 = B1src + (rowbase + (size_t)Bj1 * 128) * 128;

    const int lane    = tid & 63;
    const int wv      = tid >> 6;
    const int rowHalf = (wv >> 1) * 64;
    const int colHalf = (wv & 1) * 64;
    const int fm      = lane & 15;
    const int kq      = lane >> 4;
    const int sw      = fm & 7;

    // ---- phase S: stage A (both k-chunks, swizzled bf16) + exact Pn ----
    #pragma unroll
    for (int it = 0; it < 8; ++it) {
        int u  = it * 256 + tid;           // (row, c, jb)
        int jb = u & 7;
        int cc = (u >> 3) & 1;
        int r  = u >> 4;
        const float* g = Ap + (size_t)r * 128 + cc * 64 + jb * 8;
        float4 v0 = ((const float4*)g)[0];
        float4 v1 = ((const float4*)g)[1];
        float ss;
        ushort8 hv = cvt8(v0, v1, ss);
        *(ushort8*)(smem + cc * REG5 + r * 128 + ((jb ^ (r & 7)) * 16)) = hv;
        // full-row norm: 16 lanes = (c0 jb0..7, c1 jb0..7)
        ss += __shfl_down(ss, 8, 16);
        ss += __shfl_down(ss, 4, 16);
        ss += __shfl_down(ss, 2, 16);
        ss += __shfl_down(ss, 1, 16);
        if ((tid & 15) == 0) Pn[r] = ss;
    }
    __syncthreads();                       // the ONLY staging barrier

    f32x4 acc[4][4];

    // one full 128x128 tile: B straight from global, norms in-register
    auto tile_pass = [&](const float* Bp, bool dg) -> float {
        #pragma unroll
        for (int a2 = 0; a2 < 4; ++a2)
            #pragma unroll
            for (int b2 = 0; b2 < 4; ++b2)
                acc[a2][b2] = (f32x4){0.f, 0.f, 0.f, 0.f};
        float ssb0 = 0.f, ssb1 = 0.f, ssb2 = 0.f, ssb3 = 0.f;
        // per-lane base: row (colHalf+fm), col kq*8; fragment b2 adds 16 rows
        const float* rbase = Bp + (size_t)(colHalf + fm) * DIM + kq * 8;
        #pragma unroll
        for (int cc = 0; cc < 2; ++cc) {
            const char* Ab = smem + cc * REG5;
            const float* g0 = rbase + cc * 64;          // ks = 0
            float4 qa0 = ((const float4*)(g0       ))[0], qa1 = ((const float4*)(g0       ))[1];
            float4 qb0 = ((const float4*)(g0 + 2048))[0], qb1 = ((const float4*)(g0 + 2048))[1];
            float4 qc0 = ((const float4*)(g0 + 4096))[0], qc1 = ((const float4*)(g0 + 4096))[1];
            float4 qd0 = ((const float4*)(g0 + 6144))[0], qd1 = ((const float4*)(g0 + 6144))[1];
            float sst;
            bf16x8 bh0 = cvt8b(qa0, qa1, sst); ssb0 += sst;
            bf16x8 bh1 = cvt8b(qb0, qb1, sst); ssb1 += sst;
            bf16x8 bh2 = cvt8b(qc0, qc1, sst); ssb2 += sst;
            bf16x8 bh3 = cvt8b(qd0, qd1, sst); ssb3 += sst;
            // issue ks=1 loads before the ks=0 MFMA so latency hides under it
            const float* g1 = g0 + 32;
            float4 ra0 = ((const float4*)(g1       ))[0], ra1 = ((const float4*)(g1       ))[1];
            float4 rb0 = ((const float4*)(g1 + 2048))[0], rb1 = ((const float4*)(g1 + 2048))[1];
            float4 rc0 = ((const float4*)(g1 + 4096))[0], rc1 = ((const float4*)(g1 + 4096))[1];
            float4 rd0 = ((const float4*)(g1 + 6144))[0], rd1 = ((const float4*)(g1 + 6144))[1];
            {
                const int jx0 = (kq ^ sw) * 16;
                bf16x8 ah0 = *(const bf16x8*)(Ab + (rowHalf +  0 + fm) * 128 + jx0);
                bf16x8 ah1 = *(const bf16x8*)(Ab + (rowHalf + 16 + fm) * 128 + jx0);
                bf16x8 ah2 = *(const bf16x8*)(Ab + (rowHalf + 32 + fm) * 128 + jx0);
                bf16x8 ah3 = *(const bf16x8*)(Ab + (rowHalf + 48 + fm) * 128 + jx0);
                __builtin_amdgcn_s_setprio(1);
                MFMA16();
                __builtin_amdgcn_s_setprio(0);
            }
            bh0 = cvt8b(ra0, ra1, sst); ssb0 += sst;
            bh1 = cvt8b(rb0, rb1, sst); ssb1 += sst;
            bh2 = cvt8b(rc0, rc1, sst); ssb2 += sst;
            bh3 = cvt8b(rd0, rd1, sst); ssb3 += sst;
            {
                const int jx1 = ((4 + kq) ^ sw) * 16;
                bf16x8 ah0 = *(const bf16x8*)(Ab + (rowHalf +  0 + fm) * 128 + jx1);
                bf16x8 ah1 = *(const bf16x8*)(Ab + (rowHalf + 16 + fm) * 128 + jx1);
                bf16x8 ah2 = *(const bf16x8*)(Ab + (rowHalf + 32 + fm) * 128 + jx1);
                bf16x8 ah3 = *(const bf16x8*)(Ab + (rowHalf + 48 + fm) * 128 + jx1);
                __builtin_amdgcn_s_setprio(1);
                MFMA16();
                __builtin_amdgcn_s_setprio(0);
            }
        }
        // finish B row norms: reduce over the 4 kq lanes (same fm)
        ssb0 += __shfl_xor(ssb0, 16, 64); ssb0 += __shfl_xor(ssb0, 32, 64);
        ssb1 += __shfl_xor(ssb1, 16, 64); ssb1 += __shfl_xor(ssb1, 32, 64);
        ssb2 += __shfl_xor(ssb2, 16, 64); ssb2 += __shfl_xor(ssb2, 32, 64);
        ssb3 += __shfl_xor(ssb3, 16, 64); ssb3 += __shfl_xor(ssb3, 32, 64);
        float Qc[4] = {ssb0, ssb1, ssb2, ssb3};   // Qn[colHalf + b2*16 + fm]

        float Pr[16];
        #pragma unroll
        for (int a2 = 0; a2 < 4; ++a2)
            #pragma unroll
            for (int rg2 = 0; rg2 < 4; ++rg2)
                Pr[a2 * 4 + rg2] = Pn[rowHalf + a2 * 16 + kq * 4 + rg2];
        float ls = 0.f;
        if (dg) {
            #pragma unroll
            for (int a2 = 0; a2 < 4; ++a2)
                #pragma unroll
                for (int b2 = 0; b2 < 4; ++b2)
                    #pragma unroll
                    for (int rg2 = 0; rg2 < 4; ++rg2) {
                        float d2 = fmaf(-2.0f, acc[a2][b2][rg2], Pr[a2 * 4 + rg2] + Qc[b2]);
                        float v  = __builtin_amdgcn_sqrtf(fmaxf(d2, 0.0f));
                        if ((rowHalf + a2 * 16 + kq * 4 + rg2) == (colHalf + b2 * 16 + fm)) v = 0.f;
                        ls += v;
                    }
        } else {
            #pragma unroll
            for (int a2 = 0; a2 < 4; ++a2)
                #pragma unroll
                for (int b2 = 0; b2 < 4; ++b2)
                    #pragma unroll
                    for (int rg2 = 0; rg2 < 4; ++rg2) {
                        float d2 = fmaf(-2.0f, acc[a2][b2][rg2], Pr[a2 * 4 + rg2] + Qc[b2]);
                        ls += __builtin_amdgcn_sqrtf(fmaxf(d2, 0.0f));
                    }
        }
        return ls;
    };

    float lsum = w0 * tile_pass(Bp0, dg0);
    lsum += w1 * tile_pass(Bp1, false);

    #pragma unroll
    for (int off = 32; off > 0; off >>= 1) lsum += __shfl_down(lsum, off, 64);
    if (lane == 0) wred[wv] = lsum;
    __syncthreads();
    if (tid == 0)
        partials[bid] = wred[0] + wred[1] + wred[2] + wred[3];
}

// ---------------------------------------------------------------------------
// Fallback (in-kernel 3-term conversion, full 48 tiles/batch) if B != 128.
// ---------------------------------------------------------------------------
__global__ __launch_bounds__(256, 2)
void mmd_tile_fallback(const float* __restrict__ x, const float* __restrict__ y,
                       float* __restrict__ partials) {
    __shared__ __align__(16) char smem[4 * 128 * 144];
    __shared__ float Pn[128];
    __shared__ float Qn[128];
    __shared__ float wred[4];

    char* Ah = smem;
    char* Al = smem + 1 * 128 * 144;
    char* Bh = smem + 2 * 128 * 144;
    char* Bl = smem + 3 * 128 * 144;

    const int tid  = threadIdx.x;
    const int bid  = blockIdx.x;
    const int tj   = bid & 3;
    const int ti   = (bid >> 2) & 3;
    const int type = (bid >> 4) % 3;
    const int b    = bid / 48;

    const float* Xb = x + (size_t)b * DSAMP * DIM;
    const float* Yb = y + (size_t)b * DSAMP * DIM;
    const float* Pp; const float* Qp; float w;
    if (type == 0)      { Pp = Xb; Qp = Yb; w = 1.0f;  }
    else if (type == 1) { Pp = Xb; Qp = Xb; w = -0.5f; }
    else                { Pp = Yb; Qp = Yb; w = -0.5f; }
    Pp += (size_t)ti * 128 * DIM;
    Qp += (size_t)tj * 128 * DIM;

    {
        const float* rp = (tid < 128) ? (Pp + (size_t)tid * DIM)
                                      : (Qp + (size_t)(tid - 128) * DIM);
        float s = 0.f;
        #pragma unroll
        for (int k4 = 0; k4 < 32; ++k4) {
            float4 v = ((const float4*)rp)[k4];
            s += v.x * v.x + v.y * v.y + v.z * v.z + v.w * v.w;
        }
        if (tid < 128) Pn[tid] = s; else Qn[tid - 128] = s;
    }

    const int lane    = tid & 63;
    const int wv      = tid >> 6;
    const int rowHalf = (wv >> 1) * 64;
    const int colHalf = (wv & 1) * 64;
    const int fm      = lane & 15;
    const int kq      = lane >> 4;

    f32x4 acc[4][4];
    #pragma unroll
    for (int a2 = 0; a2 < 4; ++a2)
        #pragma unroll
        for (int b2 = 0; b2 < 4; ++b2)
            acc[a2][b2] = (f32x4){0.f, 0.f, 0.f, 0.f};

    for (int c = 0; c < 2; ++c) {
        if (c) __syncthreads();
        #pragma unroll
        for (int side = 0; side < 2; ++side) {
            const float* sp = side ? Qp : Pp;
            char* dh = side ? Bh : Ah;
            char* dl = side ? Bl : Al;
            #pragma unroll
            for (int it = 0; it < 4; ++it) {
                int u  = it * 256 + tid;
                int r  = u >> 3;
                int c8 = u & 7;
                const float* g = sp + (size_t)r * DIM + c * 64 + c8 * 8;
                float4 v0 = ((const float4*)g)[0];
                float4 v1 = ((const float4*)g)[1];
                float xs[8] = {v0.x, v0.y, v0.z, v0.w, v1.x, v1.y, v1.z, v1.w};
                ushort8 hv, lv;
                #pragma unroll
                for (int e = 0; e < 8; ++e) {
                    float xv = xs[e];
                    unsigned ub = __float_as_uint(xv);
                    unsigned hr = (ub + 0x7fffu + ((ub >> 16) & 1u)) >> 16;
                    float hf = __uint_as_float(hr << 16);
                    float rs = xv - hf;
                    unsigned ul = __float_as_uint(rs);
                    unsigned lr = (ul + 0x7fffu + ((ul >> 16) & 1u)) >> 16;
                    hv[e] = (unsigned short)hr;
                    lv[e] = (unsigned short)lr;
                }
                *(ushort8*)(dh + r * 144 + c8 * 16) = hv;
                *(ushort8*)(dl + r * 144 + c8 * 16) = lv;
            }
        }
        __syncthreads();
        #pragma unroll
        for (int ks = 0; ks < 2; ++ks) {
            const int kb2 = (ks * 32 + kq * 8) * 2;
            bf16x8 ah[4], al[4], bh[4], bl[4];
            #pragma unroll
            for (int a2 = 0; a2 < 4; ++a2) {
                int ar = rowHalf + a2 * 16 + fm;
                ah[a2] = *(const bf16x8*)(Ah + ar * 144 + kb2);
                al[a2] = *(const bf16x8*)(Al + ar * 144 + kb2);
            }
            #pragma unroll
            for (int b2 = 0; b2 < 4; ++b2) {
                int br = colHalf + b2 * 16 + fm;
                bh[b2] = *(const bf16x8*)(Bh + br * 144 + kb2);
                bl[b2] = *(const bf16x8*)(Bl + br * 144 + kb2);
            }
            #pragma unroll
            for (int a2 = 0; a2 < 4; ++a2)
                #pragma unroll
                for (int b2 = 0; b2 < 4; ++b2) {
                    acc[a2][b2] = __builtin_amdgcn_mfma_f32_16x16x32_bf16(ah[a2], bh[b2], acc[a2][b2], 0, 0, 0);
                    acc[a2][b2] = __builtin_amdgcn_mfma_f32_16x16x32_bf16(ah[a2], bl[b2], acc[a2][b2], 0, 0, 0);
                    acc[a2][b2] = __builtin_amdgcn_mfma_f32_16x16x32_bf16(al[a2], bh[b2], acc[a2][b2], 0, 0, 0);
                }
        }
    }

    const bool selfm = (type != 0) && (ti == tj);
    float lsum = 0.f;
    #pragma unroll
    for (int a2 = 0; a2 < 4; ++a2) {
        int ib = rowHalf + a2 * 16 + kq * 4;
        #pragma unroll
        for (int b2 = 0; b2 < 4; ++b2) {
            int j = colHalf + b2 * 16 + fm;
            float qn = Qn[j];
            #pragma unroll
            for (int rg = 0; rg < 4; ++rg) {
                int i = ib + rg;
                float d2 = Pn[i] + qn - 2.0f * acc[a2][b2][rg];
                if (d2 > 0.f && !(selfm && i == j)) lsum += sqrtf(d2);
            }
        }
    }
    #pragma unroll
    for (int off = 32; off > 0; off >>= 1) lsum += __shfl_down(lsum, off, 64);
    if (lane == 0) wred[wv] = lsum;
    __syncthreads();
    if (tid == 0)
        partials[bid] = (wred[0] + wred[1] + wred[2] + wred[3]) * w;
}

__global__ __launch_bounds__(256)
void mmd_finalize_kernel(const float* __restrict__ partials, int n,
                         float* __restrict__ out, double scale) {
    __shared__ double sh[256];
    double s = 0.0;
    for (int i = threadIdx.x; i < n; i += 256) s += (double)partials[i];
    sh[threadIdx.x] = s;
    __syncthreads();
    for (int off = 128; off > 0; off >>= 1) {
        if ((int)threadIdx.x < off) sh[threadIdx.x] += sh[threadIdx.x + off];
        __syncthreads();
    }
    if (threadIdx.x == 0) out[0] = (float)(sh[0] * scale);
}

extern "C" void kernel_launch(void* const* d_in, const int* in_sizes, int n_in,
                              void* d_out, int out_size, void* d_ws, size_t ws_size,
                              hipStream_t stream) {
    const float* x = (const float*)d_in[0];
    const float* y = (const float*)d_in[1];
    float* out = (float*)d_out;

    const int n = in_sizes[0];
    const int B = n / (DSAMP * DIM);       // 128
    const double scale = 1.0 / ((double)B * (double)DSAMP * (double)DSAMP);

    float* partials = (float*)d_ws;
    if (B == 128 && ws_size >= (size_t)(128 * NPAIR) * 4) {
        const int nblocks = 128 * NPAIR;   // 2304 = 3.0 exact rounds @ 3 blk/CU
        mmd_fused<<<dim3(nblocks), dim3(256), 0, stream>>>(x, y, partials);
        mmd_finalize_kernel<<<dim3(1), dim3(256), 0, stream>>>(partials, nblocks, out, scale);
    } else {
        const int nblocks = B * 48;
        mmd_tile_fallback<<<dim3(nblocks), dim3(256), 0, stream>>>(x, y, partials);
        mmd_finalize_kernel<<<dim3(1), dim3(256), 0, stream>>>(partials, nblocks, out, scale);
    }
}

// Round 8
// 271.478 us; speedup vs baseline: 1.1329x; 1.1329x over previous
//
#include <hip/hip_runtime.h>

typedef __attribute__((ext_vector_type(8))) __bf16 bf16x8;
typedef __attribute__((ext_vector_type(4))) float f32x4;
typedef __attribute__((ext_vector_type(8))) unsigned short ushort8;

#define DSAMP 512
#define DIM   128
#define REG5  16384                // one staged A region: 128 rows * 128 B (bf16, swizzled)
#define NPAIR 18                   // paired tiles per batch (2 tiles per block)

// ---------------------------------------------------------------------------
// Single-pass fused kernel, v6 = v5's verified math with spill-free codegen.
// R7 lesson: the v5 lambda (tile body called twice, non-inlined) + explicit
// 16x float4 prefetch forced 726 B/thread of scratch (428 MB writes). v6:
// (a) rolled t-loop, straight-line body, no call boundaries; (b) sequential
// load->cvt->MFMA per 8-float4 group (group dies at cvt); (c) named SSA
// values only. Peak liveness ~148 <= 168-reg cap of (256,3).
// B still never touches LDS; B row norms in-register via shfl_xor(16/32).
// 2 barriers per block total.
// ---------------------------------------------------------------------------
__constant__ unsigned char T_Asrc[NPAIR]  = {0,0,0,0,0,0,0,0, 1,1,1,1,1,1,1,1,1,1};
__constant__ unsigned char T_Ai[NPAIR]    = {0,0,1,1,1,2,2,3, 0,0,0,0,1,1,1,2,2,3};
__constant__ unsigned char T_Bsrc0[NPAIR] = {0,0,0,0,1,0,1,0, 1,1,0,0,1,1,0,1,0,1};
__constant__ unsigned char T_Bsrc1[NPAIR] = {0,0,0,1,1,0,1,1, 1,1,0,0,1,0,0,1,0,0};
__constant__ unsigned char T_Bj0[NPAIR]   = {0,2,1,3,2,2,2,3, 0,2,0,2,1,3,2,2,0,3};
__constant__ unsigned char T_Bj1[NPAIR]   = {1,3,2,1,3,3,3,3, 1,3,1,3,2,0,3,3,3,0};
// weight codes: 0 -> +1.0 (xy), 1 -> -1.0 (xx/yy off-diag), 2 -> -0.5 (diag)
__constant__ char          T_wc0[NPAIR]   = {2,1,2,1,0,2,0,2, 2,1,0,0,2,1,0,2,0,2};
__constant__ char          T_wc1[NPAIR]   = {1,1,1,0,0,1,0,0, 1,1,0,0,1,0,0,1,0,0};
__constant__ unsigned char T_d0[NPAIR]    = {1,0,1,0,0,1,0,1, 1,0,0,0,1,0,0,1,0,1};

// arrayless fp32x8 -> bf16x8 RNE convert + sum of squares (all SSA values)
__device__ __forceinline__ ushort8 cvt8(float4 v0, float4 v1, float& ss) {
    ss = v0.x * v0.x + v0.y * v0.y + v0.z * v0.z + v0.w * v0.w
       + v1.x * v1.x + v1.y * v1.y + v1.z * v1.z + v1.w * v1.w;
    ushort8 hv;
    unsigned u;
    u = __float_as_uint(v0.x); hv[0] = (unsigned short)((u + 0x7fffu + ((u >> 16) & 1u)) >> 16);
    u = __float_as_uint(v0.y); hv[1] = (unsigned short)((u + 0x7fffu + ((u >> 16) & 1u)) >> 16);
    u = __float_as_uint(v0.z); hv[2] = (unsigned short)((u + 0x7fffu + ((u >> 16) & 1u)) >> 16);
    u = __float_as_uint(v0.w); hv[3] = (unsigned short)((u + 0x7fffu + ((u >> 16) & 1u)) >> 16);
    u = __float_as_uint(v1.x); hv[4] = (unsigned short)((u + 0x7fffu + ((u >> 16) & 1u)) >> 16);
    u = __float_as_uint(v1.y); hv[5] = (unsigned short)((u + 0x7fffu + ((u >> 16) & 1u)) >> 16);
    u = __float_as_uint(v1.z); hv[6] = (unsigned short)((u + 0x7fffu + ((u >> 16) & 1u)) >> 16);
    u = __float_as_uint(v1.w); hv[7] = (unsigned short)((u + 0x7fffu + ((u >> 16) & 1u)) >> 16);
    return hv;
}

__device__ __forceinline__ bf16x8 cvt8b(float4 v0, float4 v1, float& ss) {
    ushort8 h = cvt8(v0, v1, ss);
    return __builtin_bit_cast(bf16x8, h);
}

#define MFMA16() do {                                                          \
    acc00 = __builtin_amdgcn_mfma_f32_16x16x32_bf16(ah0, bh0, acc00, 0, 0, 0); \
    acc01 = __builtin_amdgcn_mfma_f32_16x16x32_bf16(ah0, bh1, acc01, 0, 0, 0); \
    acc02 = __builtin_amdgcn_mfma_f32_16x16x32_bf16(ah0, bh2, acc02, 0, 0, 0); \
    acc03 = __builtin_amdgcn_mfma_f32_16x16x32_bf16(ah0, bh3, acc03, 0, 0, 0); \
    acc10 = __builtin_amdgcn_mfma_f32_16x16x32_bf16(ah1, bh0, acc10, 0, 0, 0); \
    acc11 = __builtin_amdgcn_mfma_f32_16x16x32_bf16(ah1, bh1, acc11, 0, 0, 0); \
    acc12 = __builtin_amdgcn_mfma_f32_16x16x32_bf16(ah1, bh2, acc12, 0, 0, 0); \
    acc13 = __builtin_amdgcn_mfma_f32_16x16x32_bf16(ah1, bh3, acc13, 0, 0, 0); \
    acc20 = __builtin_amdgcn_mfma_f32_16x16x32_bf16(ah2, bh0, acc20, 0, 0, 0); \
    acc21 = __builtin_amdgcn_mfma_f32_16x16x32_bf16(ah2, bh1, acc21, 0, 0, 0); \
    acc22 = __builtin_amdgcn_mfma_f32_16x16x32_bf16(ah2, bh2, acc22, 0, 0, 0); \
    acc23 = __builtin_amdgcn_mfma_f32_16x16x32_bf16(ah2, bh3, acc23, 0, 0, 0); \
    acc30 = __builtin_amdgcn_mfma_f32_16x16x32_bf16(ah3, bh0, acc30, 0, 0, 0); \
    acc31 = __builtin_amdgcn_mfma_f32_16x16x32_bf16(ah3, bh1, acc31, 0, 0, 0); \
    acc32 = __builtin_amdgcn_mfma_f32_16x16x32_bf16(ah3, bh2, acc32, 0, 0, 0); \
    acc33 = __builtin_amdgcn_mfma_f32_16x16x32_bf16(ah3, bh3, acc33, 0, 0, 0); \
} while (0)

// load one 8-float4 B group, convert to bh0..3, accumulate ssb0..3
#define BGROUP(goff) do {                                                      \
    const float* gg_ = rbase + (goff);                                         \
    float4 q0_ = ((const float4*)(gg_       ))[0], q1_ = ((const float4*)(gg_       ))[1]; \
    float4 q2_ = ((const float4*)(gg_ + 2048))[0], q3_ = ((const float4*)(gg_ + 2048))[1]; \
    float4 q4_ = ((const float4*)(gg_ + 4096))[0], q5_ = ((const float4*)(gg_ + 4096))[1]; \
    float4 q6_ = ((const float4*)(gg_ + 6144))[0], q7_ = ((const float4*)(gg_ + 6144))[1]; \
    float sst_;                                                                \
    bh0 = cvt8b(q0_, q1_, sst_); ssb0 += sst_;                                 \
    bh1 = cvt8b(q2_, q3_, sst_); ssb1 += sst_;                                 \
    bh2 = cvt8b(q4_, q5_, sst_); ssb2 += sst_;                                 \
    bh3 = cvt8b(q6_, q7_, sst_); ssb3 += sst_;                                 \
} while (0)

#define AGROUP(jx) do {                                                        \
    ah0 = *(const bf16x8*)(Ab + (rowHalf +  0 + fm) * 128 + (jx));             \
    ah1 = *(const bf16x8*)(Ab + (rowHalf + 16 + fm) * 128 + (jx));             \
    ah2 = *(const bf16x8*)(Ab + (rowHalf + 32 + fm) * 128 + (jx));             \
    ah3 = *(const bf16x8*)(Ab + (rowHalf + 48 + fm) * 128 + (jx));             \
} while (0)

__global__ __launch_bounds__(256, 3)
void mmd_fused(const float* __restrict__ x, const float* __restrict__ y,
               float* __restrict__ partials) {
    __shared__ __align__(16) char smem[2 * REG5];   // A c0 | A c1 (32 KB only)
    __shared__ float Pn[128];
    __shared__ float wred[4];

    const int tid = threadIdx.x;
    const int bid = blockIdx.x;
    const int xcd = bid & 7;
    const int seq = bid >> 3;            // 0..287
    const int s   = seq % NPAIR;
    const int grp = seq / NPAIR;         // 0..15
    const int b   = xcd + 8 * grp;       // batch; all 18 pair-blocks adjacent

    const int Ai  = T_Ai[s];
    const float* Asrc  = T_Asrc[s]  ? y : x;
    const float* B0src = T_Bsrc0[s] ? y : x;
    const float* B1src = T_Bsrc1[s] ? y : x;
    const int wc0 = T_wc0[s], wc1 = T_wc1[s];
    const float w0 = (wc0 == 0) ? 1.0f : ((wc0 == 1) ? -1.0f : -0.5f);
    const float w1 = (wc1 == 0) ? 1.0f : ((wc1 == 1) ? -1.0f : -0.5f);
    const bool dg0 = T_d0[s] != 0;

    const size_t rowbase = (size_t)b * 512;
    const float* Ap  = Asrc  + (rowbase + (size_t)T_Ai[s]  * 128) * 128;
    const float* Bp0 = B0src + (rowbase + (size_t)T_Bj0[s] * 128) * 128;
    const float* Bp1 = B1src + (rowbase + (size_t)T_Bj1[s] * 128) * 128;
    (void)Ai;

    const int lane    = tid & 63;
    const int wv      = tid >> 6;
    const int rowHalf = (wv >> 1) * 64;
    const int colHalf = (wv & 1) * 64;
    const int fm      = lane & 15;
    const int kq      = lane >> 4;
    const int sw      = fm & 7;

    // ---- phase S: stage A (both k-chunks, swizzled bf16) + exact Pn ----
    #pragma unroll
    for (int it = 0; it < 8; ++it) {
        int u  = it * 256 + tid;           // (row, c, jb)
        int jb = u & 7;
        int cc = (u >> 3) & 1;
        int r  = u >> 4;
        const float* g = Ap + (size_t)r * 128 + cc * 64 + jb * 8;
        float4 v0 = ((const float4*)g)[0];
        float4 v1 = ((const float4*)g)[1];
        float ss;
        ushort8 hv = cvt8(v0, v1, ss);
        *(ushort8*)(smem + cc * REG5 + r * 128 + ((jb ^ (r & 7)) * 16)) = hv;
        // full-row norm: 16 lanes = (c0 jb0..7, c1 jb0..7)
        ss += __shfl_down(ss, 8, 16);
        ss += __shfl_down(ss, 4, 16);
        ss += __shfl_down(ss, 2, 16);
        ss += __shfl_down(ss, 1, 16);
        if ((tid & 15) == 0) Pn[r] = ss;
    }
    __syncthreads();                       // the ONLY staging barrier

    const int jx0 = (kq ^ sw) * 16;
    const int jx1 = ((4 + kq) ^ sw) * 16;

    float lsum = 0.f;
    #pragma unroll 1                       // rolled: one body, two tiles
    for (int t = 0; t < 2; ++t) {
        const float* Bp = t ? Bp1 : Bp0;
        const float  wt = t ? w1  : w0;
        const bool   dg = (t == 0) && dg0;

        f32x4 acc00 = {0,0,0,0}, acc01 = {0,0,0,0}, acc02 = {0,0,0,0}, acc03 = {0,0,0,0};
        f32x4 acc10 = {0,0,0,0}, acc11 = {0,0,0,0}, acc12 = {0,0,0,0}, acc13 = {0,0,0,0};
        f32x4 acc20 = {0,0,0,0}, acc21 = {0,0,0,0}, acc22 = {0,0,0,0}, acc23 = {0,0,0,0};
        f32x4 acc30 = {0,0,0,0}, acc31 = {0,0,0,0}, acc32 = {0,0,0,0}, acc33 = {0,0,0,0};
        float ssb0 = 0.f, ssb1 = 0.f, ssb2 = 0.f, ssb3 = 0.f;
        bf16x8 bh0, bh1, bh2, bh3, ah0, ah1, ah2, ah3;

        // per-lane base: row (colHalf+fm), col kq*8; fragment b2 adds 16 rows
        const float* rbase = Bp + (size_t)(colHalf + fm) * DIM + kq * 8;
        #pragma unroll
        for (int cc = 0; cc < 2; ++cc) {
            const char* Ab = smem + cc * REG5;
            BGROUP(cc * 64);               // ks=0: load+cvt (group dies here)
            AGROUP(jx0);
            __builtin_amdgcn_s_setprio(1);
            MFMA16();
            __builtin_amdgcn_s_setprio(0);
            BGROUP(cc * 64 + 32);          // ks=1
            AGROUP(jx1);
            __builtin_amdgcn_s_setprio(1);
            MFMA16();
            __builtin_amdgcn_s_setprio(0);
        }

        // finish B row norms: reduce over the 4 kq lanes (same fm)
        ssb0 += __shfl_xor(ssb0, 16, 64); ssb0 += __shfl_xor(ssb0, 32, 64);
        ssb1 += __shfl_xor(ssb1, 16, 64); ssb1 += __shfl_xor(ssb1, 32, 64);
        ssb2 += __shfl_xor(ssb2, 16, 64); ssb2 += __shfl_xor(ssb2, 32, 64);
        ssb3 += __shfl_xor(ssb3, 16, 64); ssb3 += __shfl_xor(ssb3, 32, 64);

        float ls = 0.f;
        #pragma unroll
        for (int a2 = 0; a2 < 4; ++a2) {
            f32x4 ar0 = (a2 == 0) ? acc00 : (a2 == 1) ? acc10 : (a2 == 2) ? acc20 : acc30;
            f32x4 ar1 = (a2 == 0) ? acc01 : (a2 == 1) ? acc11 : (a2 == 2) ? acc21 : acc31;
            f32x4 ar2 = (a2 == 0) ? acc02 : (a2 == 1) ? acc12 : (a2 == 2) ? acc22 : acc32;
            f32x4 ar3 = (a2 == 0) ? acc03 : (a2 == 1) ? acc13 : (a2 == 2) ? acc23 : acc33;
            #pragma unroll
            for (int rg2 = 0; rg2 < 4; ++rg2) {
                const int   ri = rowHalf + a2 * 16 + kq * 4 + rg2;
                const float pr = Pn[ri];
                float d20 = fmaf(-2.0f, ar0[rg2], pr + ssb0);
                float d21 = fmaf(-2.0f, ar1[rg2], pr + ssb1);
                float d22 = fmaf(-2.0f, ar2[rg2], pr + ssb2);
                float d23 = fmaf(-2.0f, ar3[rg2], pr + ssb3);
                float v0s = __builtin_amdgcn_sqrtf(fmaxf(d20, 0.0f));
                float v1s = __builtin_amdgcn_sqrtf(fmaxf(d21, 0.0f));
                float v2s = __builtin_amdgcn_sqrtf(fmaxf(d22, 0.0f));
                float v3s = __builtin_amdgcn_sqrtf(fmaxf(d23, 0.0f));
                if (dg) {
                    const int cj = colHalf + fm;
                    if (ri == cj)      v0s = 0.f;
                    if (ri == cj + 16) v1s = 0.f;
                    if (ri == cj + 32) v2s = 0.f;
                    if (ri == cj + 48) v3s = 0.f;
                }
                ls += (v0s + v1s) + (v2s + v3s);
            }
        }
        lsum += wt * ls;
    }

    #pragma unroll
    for (int off = 32; off > 0; off >>= 1) lsum += __shfl_down(lsum, off, 64);
    if (lane == 0) wred[wv] = lsum;
    __syncthreads();
    if (tid == 0)
        partials[bid] = wred[0] + wred[1] + wred[2] + wred[3];
}

// ---------------------------------------------------------------------------
// Fallback (in-kernel 3-term conversion, full 48 tiles/batch) if B != 128.
// ---------------------------------------------------------------------------
__global__ __launch_bounds__(256, 2)
void mmd_tile_fallback(const float* __restrict__ x, const float* __restrict__ y,
                       float* __restrict__ partials) {
    __shared__ __align__(16) char smem[4 * 128 * 144];
    __shared__ float Pn[128];
    __shared__ float Qn[128];
    __shared__ float wred[4];

    char* Ah = smem;
    char* Al = smem + 1 * 128 * 144;
    char* Bh = smem + 2 * 128 * 144;
    char* Bl = smem + 3 * 128 * 144;

    const int tid  = threadIdx.x;
    const int bid  = blockIdx.x;
    const int tj   = bid & 3;
    const int ti   = (bid >> 2) & 3;
    const int type = (bid >> 4) % 3;
    const int b    = bid / 48;

    const float* Xb = x + (size_t)b * DSAMP * DIM;
    const float* Yb = y + (size_t)b * DSAMP * DIM;
    const float* Pp; const float* Qp; float w;
    if (type == 0)      { Pp = Xb; Qp = Yb; w = 1.0f;  }
    else if (type == 1) { Pp = Xb; Qp = Xb; w = -0.5f; }
    else                { Pp = Yb; Qp = Yb; w = -0.5f; }
    Pp += (size_t)ti * 128 * DIM;
    Qp += (size_t)tj * 128 * DIM;

    {
        const float* rp = (tid < 128) ? (Pp + (size_t)tid * DIM)
                                      : (Qp + (size_t)(tid - 128) * DIM);
        float s = 0.f;
        #pragma unroll
        for (int k4 = 0; k4 < 32; ++k4) {
            float4 v = ((const float4*)rp)[k4];
            s += v.x * v.x + v.y * v.y + v.z * v.z + v.w * v.w;
        }
        if (tid < 128) Pn[tid] = s; else Qn[tid - 128] = s;
    }

    const int lane    = tid & 63;
    const int wv      = tid >> 6;
    const int rowHalf = (wv >> 1) * 64;
    const int colHalf = (wv & 1) * 64;
    const int fm      = lane & 15;
    const int kq      = lane >> 4;

    f32x4 acc[4][4];
    #pragma unroll
    for (int a2 = 0; a2 < 4; ++a2)
        #pragma unroll
        for (int b2 = 0; b2 < 4; ++b2)
            acc[a2][b2] = (f32x4){0.f, 0.f, 0.f, 0.f};

    for (int c = 0; c < 2; ++c) {
        if (c) __syncthreads();
        #pragma unroll
        for (int side = 0; side < 2; ++side) {
            const float* sp = side ? Qp : Pp;
            char* dh = side ? Bh : Ah;
            char* dl = side ? Bl : Al;
            #pragma unroll
            for (int it = 0; it < 4; ++it) {
                int u  = it * 256 + tid;
                int r  = u >> 3;
                int c8 = u & 7;
                const float* g = sp + (size_t)r * DIM + c * 64 + c8 * 8;
                float4 v0 = ((const float4*)g)[0];
                float4 v1 = ((const float4*)g)[1];
                float xs[8] = {v0.x, v0.y, v0.z, v0.w, v1.x, v1.y, v1.z, v1.w};
                ushort8 hv, lv;
                #pragma unroll
                for (int e = 0; e < 8; ++e) {
                    float xv = xs[e];
                    unsigned ub = __float_as_uint(xv);
                    unsigned hr = (ub + 0x7fffu + ((ub >> 16) & 1u)) >> 16;
                    float hf = __uint_as_float(hr << 16);
                    float rs = xv - hf;
                    unsigned ul = __float_as_uint(rs);
                    unsigned lr = (ul + 0x7fffu + ((ul >> 16) & 1u)) >> 16;
                    hv[e] = (unsigned short)hr;
                    lv[e] = (unsigned short)lr;
                }
                *(ushort8*)(dh + r * 144 + c8 * 16) = hv;
                *(ushort8*)(dl + r * 144 + c8 * 16) = lv;
            }
        }
        __syncthreads();
        #pragma unroll
        for (int ks = 0; ks < 2; ++ks) {
            const int kb2 = (ks * 32 + kq * 8) * 2;
            bf16x8 ah[4], al[4], bh[4], bl[4];
            #pragma unroll
            for (int a2 = 0; a2 < 4; ++a2) {
                int ar = rowHalf + a2 * 16 + fm;
                ah[a2] = *(const bf16x8*)(Ah + ar * 144 + kb2);
                al[a2] = *(const bf16x8*)(Al + ar * 144 + kb2);
            }
            #pragma unroll
            for (int b2 = 0; b2 < 4; ++b2) {
                int br = colHalf + b2 * 16 + fm;
                bh[b2] = *(const bf16x8*)(Bh + br * 144 + kb2);
                bl[b2] = *(const bf16x8*)(Bl + br * 144 + kb2);
            }
            #pragma unroll
            for (int a2 = 0; a2 < 4; ++a2)
                #pragma unroll
                for (int b2 = 0; b2 < 4; ++b2) {
                    acc[a2][b2] = __builtin_amdgcn_mfma_f32_16x16x32_bf16(ah[a2], bh[b2], acc[a2][b2], 0, 0, 0);
                    acc[a2][b2] = __builtin_amdgcn_mfma_f32_16x16x32_bf16(ah[a2], bl[b2], acc[a2][b2], 0, 0, 0);
                    acc[a2][b2] = __builtin_amdgcn_mfma_f32_16x16x32_bf16(al[a2], bh[b2], acc[a2][b2], 0, 0, 0);
                }
        }
    }

    const bool selfm = (type != 0) && (ti == tj);
    float lsum = 0.f;
    #pragma unroll
    for (int a2 = 0; a2 < 4; ++a2) {
        int ib = rowHalf + a2 * 16 + kq * 4;
        #pragma unroll
        for (int b2 = 0; b2 < 4; ++b2) {
            int j = colHalf + b2 * 16 + fm;
            float qn = Qn[j];
            #pragma unroll
            for (int rg = 0; rg < 4; ++rg) {
                int i = ib + rg;
                float d2 = Pn[i] + qn - 2.0f * acc[a2][b2][rg];
                if (d2 > 0.f && !(selfm && i == j)) lsum += sqrtf(d2);
            }
        }
    }
    #pragma unroll
    for (int off = 32; off > 0; off >>= 1) lsum += __shfl_down(lsum, off, 64);
    if (lane == 0) wred[wv] = lsum;
    __syncthreads();
    if (tid == 0)
        partials[bid] = (wred[0] + wred[1] + wred[2] + wred[3]) * w;
}

__global__ __launch_bounds__(256)
void mmd_finalize_kernel(const float* __restrict__ partials, int n,
                         float* __restrict__ out, double scale) {
    __shared__ double sh[256];
    double s = 0.0;
    for (int i = threadIdx.x; i < n; i += 256) s += (double)partials[i];
    sh[threadIdx.x] = s;
    __syncthreads();
    for (int off = 128; off > 0; off >>= 1) {
        if ((int)threadIdx.x < off) sh[threadIdx.x] += sh[threadIdx.x + off];
        __syncthreads();
    }
    if (threadIdx.x == 0) out[0] = (float)(sh[0] * scale);
}

extern "C" void kernel_launch(void* const* d_in, const int* in_sizes, int n_in,
                              void* d_out, int out_size, void* d_ws, size_t ws_size,
                              hipStream_t stream) {
    const float* x = (const float*)d_in[0];
    const float* y = (const float*)d_in[1];
    float* out = (float*)d_out;

    const int n = in_sizes[0];
    const int B = n / (DSAMP * DIM);       // 128
    const double scale = 1.0 / ((double)B * (double)DSAMP * (double)DSAMP);

    float* partials = (float*)d_ws;
    if (B == 128 && ws_size >= (size_t)(128 * NPAIR) * 4) {
        const int nblocks = 128 * NPAIR;   // 2304 = 3.0 exact rounds @ 3 blk/CU
        mmd_fused<<<dim3(nblocks), dim3(256), 0, stream>>>(x, y, partials);
        mmd_finalize_kernel<<<dim3(1), dim3(256), 0, stream>>>(partials, nblocks, out, scale);
    } else {
        const int nblocks = B * 48;
        mmd_tile_fallback<<<dim3(nblocks), dim3(256), 0, stream>>>(x, y, partials);
        mmd_finalize_kernel<<<dim3(1), dim3(256), 0, stream>>>(partials, nblocks, out, scale);
    }
}

// Round 9
// 181.138 us; speedup vs baseline: 1.6979x; 1.4987x over previous
//
#include <hip/hip_runtime.h>

typedef __attribute__((ext_vector_type(8))) __bf16 bf16x8;
typedef __attribute__((ext_vector_type(4))) float f32x4;
typedef __attribute__((ext_vector_type(8))) unsigned short ushort8;

#define DSAMP 512
#define DIM   128
#define REG5  16384                // one staged A region: 128 rows * 128 B (bf16, swizzled)
#define NPAIR 18                   // paired tiles per batch (2 tiles per block)

// ---------------------------------------------------------------------------
// Single-pass fused kernel, v7 = v6 byte-identical EXCEPT __launch_bounds__
// (256,3) -> (256,2). R8 evidence: VGPR_Count pinned at 84 across ALL source
// variants (R4-R8) with 200+ MB scratch -> the 168-reg cap of (256,3) is the
// binding constraint, not source structure. At (256,2) the budget is 256
// unified regs; v6's worst-case liveness (~200 incl. batched loads +
// addressing) fits. Single-variable experiment per R4's pre-commitment.
// ---------------------------------------------------------------------------
__constant__ unsigned char T_Asrc[NPAIR]  = {0,0,0,0,0,0,0,0, 1,1,1,1,1,1,1,1,1,1};
__constant__ unsigned char T_Ai[NPAIR]    = {0,0,1,1,1,2,2,3, 0,0,0,0,1,1,1,2,2,3};
__constant__ unsigned char T_Bsrc0[NPAIR] = {0,0,0,0,1,0,1,0, 1,1,0,0,1,1,0,1,0,1};
__constant__ unsigned char T_Bsrc1[NPAIR] = {0,0,0,1,1,0,1,1, 1,1,0,0,1,0,0,1,0,0};
__constant__ unsigned char T_Bj0[NPAIR]   = {0,2,1,3,2,2,2,3, 0,2,0,2,1,3,2,2,0,3};
__constant__ unsigned char T_Bj1[NPAIR]   = {1,3,2,1,3,3,3,3, 1,3,1,3,2,0,3,3,3,0};
// weight codes: 0 -> +1.0 (xy), 1 -> -1.0 (xx/yy off-diag), 2 -> -0.5 (diag)
__constant__ char          T_wc0[NPAIR]   = {2,1,2,1,0,2,0,2, 2,1,0,0,2,1,0,2,0,2};
__constant__ char          T_wc1[NPAIR]   = {1,1,1,0,0,1,0,0, 1,1,0,0,1,0,0,1,0,0};
__constant__ unsigned char T_d0[NPAIR]    = {1,0,1,0,0,1,0,1, 1,0,0,0,1,0,0,1,0,1};

// arrayless fp32x8 -> bf16x8 RNE convert + sum of squares (all SSA values)
__device__ __forceinline__ ushort8 cvt8(float4 v0, float4 v1, float& ss) {
    ss = v0.x * v0.x + v0.y * v0.y + v0.z * v0.z + v0.w * v0.w
       + v1.x * v1.x + v1.y * v1.y + v1.z * v1.z + v1.w * v1.w;
    ushort8 hv;
    unsigned u;
    u = __float_as_uint(v0.x); hv[0] = (unsigned short)((u + 0x7fffu + ((u >> 16) & 1u)) >> 16);
    u = __float_as_uint(v0.y); hv[1] = (unsigned short)((u + 0x7fffu + ((u >> 16) & 1u)) >> 16);
    u = __float_as_uint(v0.z); hv[2] = (unsigned short)((u + 0x7fffu + ((u >> 16) & 1u)) >> 16);
    u = __float_as_uint(v0.w); hv[3] = (unsigned short)((u + 0x7fffu + ((u >> 16) & 1u)) >> 16);
    u = __float_as_uint(v1.x); hv[4] = (unsigned short)((u + 0x7fffu + ((u >> 16) & 1u)) >> 16);
    u = __float_as_uint(v1.y); hv[5] = (unsigned short)((u + 0x7fffu + ((u >> 16) & 1u)) >> 16);
    u = __float_as_uint(v1.z); hv[6] = (unsigned short)((u + 0x7fffu + ((u >> 16) & 1u)) >> 16);
    u = __float_as_uint(v1.w); hv[7] = (unsigned short)((u + 0x7fffu + ((u >> 16) & 1u)) >> 16);
    return hv;
}

__device__ __forceinline__ bf16x8 cvt8b(float4 v0, float4 v1, float& ss) {
    ushort8 h = cvt8(v0, v1, ss);
    return __builtin_bit_cast(bf16x8, h);
}

#define MFMA16() do {                                                          \
    acc00 = __builtin_amdgcn_mfma_f32_16x16x32_bf16(ah0, bh0, acc00, 0, 0, 0); \
    acc01 = __builtin_amdgcn_mfma_f32_16x16x32_bf16(ah0, bh1, acc01, 0, 0, 0); \
    acc02 = __builtin_amdgcn_mfma_f32_16x16x32_bf16(ah0, bh2, acc02, 0, 0, 0); \
    acc03 = __builtin_amdgcn_mfma_f32_16x16x32_bf16(ah0, bh3, acc03, 0, 0, 0); \
    acc10 = __builtin_amdgcn_mfma_f32_16x16x32_bf16(ah1, bh0, acc10, 0, 0, 0); \
    acc11 = __builtin_amdgcn_mfma_f32_16x16x32_bf16(ah1, bh1, acc11, 0, 0, 0); \
    acc12 = __builtin_amdgcn_mfma_f32_16x16x32_bf16(ah1, bh2, acc12, 0, 0, 0); \
    acc13 = __builtin_amdgcn_mfma_f32_16x16x32_bf16(ah1, bh3, acc13, 0, 0, 0); \
    acc20 = __builtin_amdgcn_mfma_f32_16x16x32_bf16(ah2, bh0, acc20, 0, 0, 0); \
    acc21 = __builtin_amdgcn_mfma_f32_16x16x32_bf16(ah2, bh1, acc21, 0, 0, 0); \
    acc22 = __builtin_amdgcn_mfma_f32_16x16x32_bf16(ah2, bh2, acc22, 0, 0, 0); \
    acc23 = __builtin_amdgcn_mfma_f32_16x16x32_bf16(ah2, bh3, acc23, 0, 0, 0); \
    acc30 = __builtin_amdgcn_mfma_f32_16x16x32_bf16(ah3, bh0, acc30, 0, 0, 0); \
    acc31 = __builtin_amdgcn_mfma_f32_16x16x32_bf16(ah3, bh1, acc31, 0, 0, 0); \
    acc32 = __builtin_amdgcn_mfma_f32_16x16x32_bf16(ah3, bh2, acc32, 0, 0, 0); \
    acc33 = __builtin_amdgcn_mfma_f32_16x16x32_bf16(ah3, bh3, acc33, 0, 0, 0); \
} while (0)

// load one 8-float4 B group, convert to bh0..3, accumulate ssb0..3
#define BGROUP(goff) do {                                                      \
    const float* gg_ = rbase + (goff);                                         \
    float4 q0_ = ((const float4*)(gg_       ))[0], q1_ = ((const float4*)(gg_       ))[1]; \
    float4 q2_ = ((const float4*)(gg_ + 2048))[0], q3_ = ((const float4*)(gg_ + 2048))[1]; \
    float4 q4_ = ((const float4*)(gg_ + 4096))[0], q5_ = ((const float4*)(gg_ + 4096))[1]; \
    float4 q6_ = ((const float4*)(gg_ + 6144))[0], q7_ = ((const float4*)(gg_ + 6144))[1]; \
    float sst_;                                                                \
    bh0 = cvt8b(q0_, q1_, sst_); ssb0 += sst_;                                 \
    bh1 = cvt8b(q2_, q3_, sst_); ssb1 += sst_;                                 \
    bh2 = cvt8b(q4_, q5_, sst_); ssb2 += sst_;                                 \
    bh3 = cvt8b(q6_, q7_, sst_); ssb3 += sst_;                                 \
} while (0)

#define AGROUP(jx) do {                                                        \
    ah0 = *(const bf16x8*)(Ab + (rowHalf +  0 + fm) * 128 + (jx));             \
    ah1 = *(const bf16x8*)(Ab + (rowHalf + 16 + fm) * 128 + (jx));             \
    ah2 = *(const bf16x8*)(Ab + (rowHalf + 32 + fm) * 128 + (jx));             \
    ah3 = *(const bf16x8*)(Ab + (rowHalf + 48 + fm) * 128 + (jx));             \
} while (0)

__global__ __launch_bounds__(256, 2)
void mmd_fused(const float* __restrict__ x, const float* __restrict__ y,
               float* __restrict__ partials) {
    __shared__ __align__(16) char smem[2 * REG5];   // A c0 | A c1 (32 KB only)
    __shared__ float Pn[128];
    __shared__ float wred[4];

    const int tid = threadIdx.x;
    const int bid = blockIdx.x;
    const int xcd = bid & 7;
    const int seq = bid >> 3;            // 0..287
    const int s   = seq % NPAIR;
    const int grp = seq / NPAIR;         // 0..15
    const int b   = xcd + 8 * grp;       // batch; all 18 pair-blocks adjacent

    const float* Asrc  = T_Asrc[s]  ? y : x;
    const float* B0src = T_Bsrc0[s] ? y : x;
    const float* B1src = T_Bsrc1[s] ? y : x;
    const int wc0 = T_wc0[s], wc1 = T_wc1[s];
    const float w0 = (wc0 == 0) ? 1.0f : ((wc0 == 1) ? -1.0f : -0.5f);
    const float w1 = (wc1 == 0) ? 1.0f : ((wc1 == 1) ? -1.0f : -0.5f);
    const bool dg0 = T_d0[s] != 0;

    const size_t rowbase = (size_t)b * 512;
    const float* Ap  = Asrc  + (rowbase + (size_t)T_Ai[s]  * 128) * 128;
    const float* Bp0 = B0src + (rowbase + (size_t)T_Bj0[s] * 128) * 128;
    const float* Bp1 = B1src + (rowbase + (size_t)T_Bj1[s] * 128) * 128;

    const int lane    = tid & 63;
    const int wv      = tid >> 6;
    const int rowHalf = (wv >> 1) * 64;
    const int colHalf = (wv & 1) * 64;
    const int fm      = lane & 15;
    const int kq      = lane >> 4;
    const int sw      = fm & 7;

    // ---- phase S: stage A (both k-chunks, swizzled bf16) + exact Pn ----
    #pragma unroll
    for (int it = 0; it < 8; ++it) {
        int u  = it * 256 + tid;           // (row, c, jb)
        int jb = u & 7;
        int cc = (u >> 3) & 1;
        int r  = u >> 4;
        const float* g = Ap + (size_t)r * 128 + cc * 64 + jb * 8;
        float4 v0 = ((const float4*)g)[0];
        float4 v1 = ((const float4*)g)[1];
        float ss;
        ushort8 hv = cvt8(v0, v1, ss);
        *(ushort8*)(smem + cc * REG5 + r * 128 + ((jb ^ (r & 7)) * 16)) = hv;
        // full-row norm: 16 lanes = (c0 jb0..7, c1 jb0..7)
        ss += __shfl_down(ss, 8, 16);
        ss += __shfl_down(ss, 4, 16);
        ss += __shfl_down(ss, 2, 16);
        ss += __shfl_down(ss, 1, 16);
        if ((tid & 15) == 0) Pn[r] = ss;
    }
    __syncthreads();                       // the ONLY staging barrier

    const int jx0 = (kq ^ sw) * 16;
    const int jx1 = ((4 + kq) ^ sw) * 16;

    float lsum = 0.f;
    #pragma unroll 1                       // rolled: one body, two tiles
    for (int t = 0; t < 2; ++t) {
        const float* Bp = t ? Bp1 : Bp0;
        const float  wt = t ? w1  : w0;
        const bool   dg = (t == 0) && dg0;

        f32x4 acc00 = {0,0,0,0}, acc01 = {0,0,0,0}, acc02 = {0,0,0,0}, acc03 = {0,0,0,0};
        f32x4 acc10 = {0,0,0,0}, acc11 = {0,0,0,0}, acc12 = {0,0,0,0}, acc13 = {0,0,0,0};
        f32x4 acc20 = {0,0,0,0}, acc21 = {0,0,0,0}, acc22 = {0,0,0,0}, acc23 = {0,0,0,0};
        f32x4 acc30 = {0,0,0,0}, acc31 = {0,0,0,0}, acc32 = {0,0,0,0}, acc33 = {0,0,0,0};
        float ssb0 = 0.f, ssb1 = 0.f, ssb2 = 0.f, ssb3 = 0.f;
        bf16x8 bh0, bh1, bh2, bh3, ah0, ah1, ah2, ah3;

        // per-lane base: row (colHalf+fm), col kq*8; fragment b2 adds 16 rows
        const float* rbase = Bp + (size_t)(colHalf + fm) * DIM + kq * 8;
        #pragma unroll
        for (int cc = 0; cc < 2; ++cc) {
            const char* Ab = smem + cc * REG5;
            BGROUP(cc * 64);               // ks=0: load+cvt (group dies here)
            AGROUP(jx0);
            __builtin_amdgcn_s_setprio(1);
            MFMA16();
            __builtin_amdgcn_s_setprio(0);
            BGROUP(cc * 64 + 32);          // ks=1
            AGROUP(jx1);
            __builtin_amdgcn_s_setprio(1);
            MFMA16();
            __builtin_amdgcn_s_setprio(0);
        }

        // finish B row norms: reduce over the 4 kq lanes (same fm)
        ssb0 += __shfl_xor(ssb0, 16, 64); ssb0 += __shfl_xor(ssb0, 32, 64);
        ssb1 += __shfl_xor(ssb1, 16, 64); ssb1 += __shfl_xor(ssb1, 32, 64);
        ssb2 += __shfl_xor(ssb2, 16, 64); ssb2 += __shfl_xor(ssb2, 32, 64);
        ssb3 += __shfl_xor(ssb3, 16, 64); ssb3 += __shfl_xor(ssb3, 32, 64);

        float ls = 0.f;
        #pragma unroll
        for (int a2 = 0; a2 < 4; ++a2) {
            f32x4 ar0 = (a2 == 0) ? acc00 : (a2 == 1) ? acc10 : (a2 == 2) ? acc20 : acc30;
            f32x4 ar1 = (a2 == 0) ? acc01 : (a2 == 1) ? acc11 : (a2 == 2) ? acc21 : acc31;
            f32x4 ar2 = (a2 == 0) ? acc02 : (a2 == 1) ? acc12 : (a2 == 2) ? acc22 : acc32;
            f32x4 ar3 = (a2 == 0) ? acc03 : (a2 == 1) ? acc13 : (a2 == 2) ? acc23 : acc33;
            #pragma unroll
            for (int rg2 = 0; rg2 < 4; ++rg2) {
                const int   ri = rowHalf + a2 * 16 + kq * 4 + rg2;
                const float pr = Pn[ri];
                float d20 = fmaf(-2.0f, ar0[rg2], pr + ssb0);
                float d21 = fmaf(-2.0f, ar1[rg2], pr + ssb1);
                float d22 = fmaf(-2.0f, ar2[rg2], pr + ssb2);
                float d23 = fmaf(-2.0f, ar3[rg2], pr + ssb3);
                float v0s = __builtin_amdgcn_sqrtf(fmaxf(d20, 0.0f));
                float v1s = __builtin_amdgcn_sqrtf(fmaxf(d21, 0.0f));
                float v2s = __builtin_amdgcn_sqrtf(fmaxf(d22, 0.0f));
                float v3s = __builtin_amdgcn_sqrtf(fmaxf(d23, 0.0f));
                if (dg) {
                    const int cj = colHalf + fm;
                    if (ri == cj)      v0s = 0.f;
                    if (ri == cj + 16) v1s = 0.f;
                    if (ri == cj + 32) v2s = 0.f;
                    if (ri == cj + 48) v3s = 0.f;
                }
                ls += (v0s + v1s) + (v2s + v3s);
            }
        }
        lsum += wt * ls;
    }

    #pragma unroll
    for (int off = 32; off > 0; off >>= 1) lsum += __shfl_down(lsum, off, 64);
    if (lane == 0) wred[wv] = lsum;
    __syncthreads();
    if (tid == 0)
        partials[bid] = wred[0] + wred[1] + wred[2] + wred[3];
}

// ---------------------------------------------------------------------------
// Fallback (in-kernel 3-term conversion, full 48 tiles/batch) if B != 128.
// ---------------------------------------------------------------------------
__global__ __launch_bounds__(256, 2)
void mmd_tile_fallback(const float* __restrict__ x, const float* __restrict__ y,
                       float* __restrict__ partials) {
    __shared__ __align__(16) char smem[4 * 128 * 144];
    __shared__ float Pn[128];
    __shared__ float Qn[128];
    __shared__ float wred[4];

    char* Ah = smem;
    char* Al = smem + 1 * 128 * 144;
    char* Bh = smem + 2 * 128 * 144;
    char* Bl = smem + 3 * 128 * 144;

    const int tid  = threadIdx.x;
    const int bid  = blockIdx.x;
    const int tj   = bid & 3;
    const int ti   = (bid >> 2) & 3;
    const int type = (bid >> 4) % 3;
    const int b    = bid / 48;

    const float* Xb = x + (size_t)b * DSAMP * DIM;
    const float* Yb = y + (size_t)b * DSAMP * DIM;
    const float* Pp; const float* Qp; float w;
    if (type == 0)      { Pp = Xb; Qp = Yb; w = 1.0f;  }
    else if (type == 1) { Pp = Xb; Qp = Xb; w = -0.5f; }
    else                { Pp = Yb; Qp = Yb; w = -0.5f; }
    Pp += (size_t)ti * 128 * DIM;
    Qp += (size_t)tj * 128 * DIM;

    {
        const float* rp = (tid < 128) ? (Pp + (size_t)tid * DIM)
                                      : (Qp + (size_t)(tid - 128) * DIM);
        float s = 0.f;
        #pragma unroll
        for (int k4 = 0; k4 < 32; ++k4) {
            float4 v = ((const float4*)rp)[k4];
            s += v.x * v.x + v.y * v.y + v.z * v.z + v.w * v.w;
        }
        if (tid < 128) Pn[tid] = s; else Qn[tid - 128] = s;
    }

    const int lane    = tid & 63;
    const int wv      = tid >> 6;
    const int rowHalf = (wv >> 1) * 64;
    const int colHalf = (wv & 1) * 64;
    const int fm      = lane & 15;
    const int kq      = lane >> 4;

    f32x4 acc[4][4];
    #pragma unroll
    for (int a2 = 0; a2 < 4; ++a2)
        #pragma unroll
        for (int b2 = 0; b2 < 4; ++b2)
            acc[a2][b2] = (f32x4){0.f, 0.f, 0.f, 0.f};

    for (int c = 0; c < 2; ++c) {
        if (c) __syncthreads();
        #pragma unroll
        for (int side = 0; side < 2; ++side) {
            const float* sp = side ? Qp : Pp;
            char* dh = side ? Bh : Ah;
            char* dl = side ? Bl : Al;
            #pragma unroll
            for (int it = 0; it < 4; ++it) {
                int u  = it * 256 + tid;
                int r  = u >> 3;
                int c8 = u & 7;
                const float* g = sp + (size_t)r * DIM + c * 64 + c8 * 8;
                float4 v0 = ((const float4*)g)[0];
                float4 v1 = ((const float4*)g)[1];
                float xs[8] = {v0.x, v0.y, v0.z, v0.w, v1.x, v1.y, v1.z, v1.w};
                ushort8 hv, lv;
                #pragma unroll
                for (int e = 0; e < 8; ++e) {
                    float xv = xs[e];
                    unsigned ub = __float_as_uint(xv);
                    unsigned hr = (ub + 0x7fffu + ((ub >> 16) & 1u)) >> 16;
                    float hf = __uint_as_float(hr << 16);
                    float rs = xv - hf;
                    unsigned ul = __float_as_uint(rs);
                    unsigned lr = (ul + 0x7fffu + ((ul >> 16) & 1u)) >> 16;
                    hv[e] = (unsigned short)hr;
                    lv[e] = (unsigned short)lr;
                }
                *(ushort8*)(dh + r * 144 + c8 * 16) = hv;
                *(ushort8*)(dl + r * 144 + c8 * 16) = lv;
            }
        }
        __syncthreads();
        #pragma unroll
        for (int ks = 0; ks < 2; ++ks) {
            const int kb2 = (ks * 32 + kq * 8) * 2;
            bf16x8 ah[4], al[4], bh[4], bl[4];
            #pragma unroll
            for (int a2 = 0; a2 < 4; ++a2) {
                int ar = rowHalf + a2 * 16 + fm;
                ah[a2] = *(const bf16x8*)(Ah + ar * 144 + kb2);
                al[a2] = *(const bf16x8*)(Al + ar * 144 + kb2);
            }
            #pragma unroll
            for (int b2 = 0; b2 < 4; ++b2) {
                int br = colHalf + b2 * 16 + fm;
                bh[b2] = *(const bf16x8*)(Bh + br * 144 + kb2);
                bl[b2] = *(const bf16x8*)(Bl + br * 144 + kb2);
            }
            #pragma unroll
            for (int a2 = 0; a2 < 4; ++a2)
                #pragma unroll
                for (int b2 = 0; b2 < 4; ++b2) {
                    acc[a2][b2] = __builtin_amdgcn_mfma_f32_16x16x32_bf16(ah[a2], bh[b2], acc[a2][b2], 0, 0, 0);
                    acc[a2][b2] = __builtin_amdgcn_mfma_f32_16x16x32_bf16(ah[a2], bl[b2], acc[a2][b2], 0, 0, 0);
                    acc[a2][b2] = __builtin_amdgcn_mfma_f32_16x16x32_bf16(al[a2], bh[b2], acc[a2][b2], 0, 0, 0);
                }
        }
    }

    const bool selfm = (type != 0) && (ti == tj);
    float lsum = 0.f;
    #pragma unroll
    for (int a2 = 0; a2 < 4; ++a2) {
        int ib = rowHalf + a2 * 16 + kq * 4;
        #pragma unroll
        for (int b2 = 0; b2 < 4; ++b2) {
            int j = colHalf + b2 * 16 + fm;
            float qn = Qn[j];
            #pragma unroll
            for (int rg = 0; rg < 4; ++rg) {
                int i = ib + rg;
                float d2 = Pn[i] + qn - 2.0f * acc[a2][b2][rg];
                if (d2 > 0.f && !(selfm && i == j)) lsum += sqrtf(d2);
            }
        }
    }
    #pragma unroll
    for (int off = 32; off > 0; off >>= 1) lsum += __shfl_down(lsum, off, 64);
    if (lane == 0) wred[wv] = lsum;
    __syncthreads();
    if (tid == 0)
        partials[bid] = (wred[0] + wred[1] + wred[2] + wred[3]) * w;
}

__global__ __launch_bounds__(256)
void mmd_finalize_kernel(const float* __restrict__ partials, int n,
                         float* __restrict__ out, double scale) {
    __shared__ double sh[256];
    double s = 0.0;
    for (int i = threadIdx.x; i < n; i += 256) s += (double)partials[i];
    sh[threadIdx.x] = s;
    __syncthreads();
    for (int off = 128; off > 0; off >>= 1) {
        if ((int)threadIdx.x < off) sh[threadIdx.x] += sh[threadIdx.x + off];
        __syncthreads();
    }
    if (threadIdx.x == 0) out[0] = (float)(sh[0] * scale);
}

extern "C" void kernel_launch(void* const* d_in, const int* in_sizes, int n_in,
                              void* d_out, int out_size, void* d_ws, size_t ws_size,
                              hipStream_t stream) {
    const float* x = (const float*)d_in[0];
    const float* y = (const float*)d_in[1];
    float* out = (float*)d_out;

    const int n = in_sizes[0];
    const int B = n / (DSAMP * DIM);       // 128
    const double scale = 1.0 / ((double)B * (double)DSAMP * (double)DSAMP);

    float* partials = (float*)d_ws;
    if (B == 128 && ws_size >= (size_t)(128 * NPAIR) * 4) {
        const int nblocks = 128 * NPAIR;   // 2304
        mmd_fused<<<dim3(nblocks), dim3(256), 0, stream>>>(x, y, partials);
        mmd_finalize_kernel<<<dim3(1), dim3(256), 0, stream>>>(partials, nblocks, out, scale);
    } else {
        const int nblocks = B * 48;
        mmd_tile_fallback<<<dim3(nblocks), dim3(256), 0, stream>>>(x, y, partials);
        mmd_finalize_kernel<<<dim3(1), dim3(256), 0, stream>>>(partials, nblocks, out, scale);
    }
}